// Round 1
// baseline (167.387 us; speedup 1.0000x reference)
//
#include <hip/hip_runtime.h>

constexpr int FIELD = 26;
constexpr int EDIM  = 32;
constexpr int NPAIR = 325;   // C(26,2)
constexpr int BT    = 32;    // batch rows per block

__global__ __launch_bounds__(256) void bilinear_kernel(
    const float* __restrict__ x,     // [B][26][32]
    const float* __restrict__ W,     // [325][32][32]  (W[p][e][d])
    const float* __restrict__ bias,  // [325][32]
    float* __restrict__ out)         // [B][325][32]
{
    const int p  = blockIdx.y;
    const int b0 = blockIdx.x * BT;

    // triu_indices(26, k=1), row-major: recover (fi, fj) from p (wave-uniform).
    int fi = 0, rem = p;
    #pragma unroll 1
    while (rem >= FIELD - 1 - fi) { rem -= FIELD - 1 - fi; ++fi; }
    const int fj = fi + 1 + rem;

    __shared__ float xi[BT][EDIM];
    __shared__ float xj[BT][EDIM];

    const int tid = threadIdx.x;

    // Stage x tiles: 2 * 32 rows * 128 B, coalesced float4 (2 loads/thread).
    {
        const int s = tid >> 3;          // batch row within tile, 0..31
        const int c = (tid & 7) << 2;    // d offset, 0..28 step 4
        const float4 vi = *(const float4*)(x + (((size_t)(b0 + s)) * FIELD + fi) * EDIM + c);
        const float4 vj = *(const float4*)(x + (((size_t)(b0 + s)) * FIELD + fj) * EDIM + c);
        *(float4*)(&xi[s][c]) = vi;
        *(float4*)(&xj[s][c]) = vj;
    }

    const int e  = tid & (EDIM - 1);     // output embed index, 0..31
    const int bg = tid >> 5;             // batch group, 0..7 (4 rows each)

    // W row for this e into registers; 8 threads/block share a row -> L1 hits.
    float w[EDIM];
    const float* wrow = W + ((size_t)p * EDIM + e) * EDIM;
    #pragma unroll
    for (int d = 0; d < EDIM; d += 4) {
        const float4 w4 = *(const float4*)(wrow + d);
        w[d] = w4.x; w[d + 1] = w4.y; w[d + 2] = w4.z; w[d + 3] = w4.w;
    }
    const float be = bias[(size_t)p * EDIM + e];

    __syncthreads();

    #pragma unroll
    for (int k = 0; k < 4; ++k) {
        const int br = bg * 4 + k;
        float acc = 0.f;
        #pragma unroll
        for (int d = 0; d < EDIM; d += 4) {
            const float4 xv = *(const float4*)(&xi[br][d]);  // broadcast LDS read
            acc = fmaf(xv.x, w[d],     acc);
            acc = fmaf(xv.y, w[d + 1], acc);
            acc = fmaf(xv.z, w[d + 2], acc);
            acc = fmaf(xv.w, w[d + 3], acc);
        }
        const float r = (acc + be) * xj[br][e];
        out[(((size_t)(b0 + br)) * NPAIR + p) * EDIM + e] = r;
    }
}

extern "C" void kernel_launch(void* const* d_in, const int* in_sizes, int n_in,
                              void* d_out, int out_size, void* d_ws, size_t ws_size,
                              hipStream_t stream) {
    const float* x    = (const float*)d_in[0];
    const float* W    = (const float*)d_in[1];
    const float* bias = (const float*)d_in[2];
    float* out        = (float*)d_out;

    const int B = in_sizes[0] / (FIELD * EDIM);   // 4096
    dim3 grid(B / BT, NPAIR);
    bilinear_kernel<<<grid, dim3(256), 0, stream>>>(x, W, bias, out);
}

// Round 2
// 63.545 us; speedup vs baseline: 2.6341x; 2.6341x over previous
//
#include <hip/hip_runtime.h>

constexpr int FIELD = 26;
constexpr int EDIM  = 32;
constexpr int NPAIR = 325;   // C(26,2)
constexpr int BT    = 64;    // batch rows per block
constexpr int XPAD  = 36;    // padded LDS row length in floats (16B-aligned, bank-spread)

__global__ __launch_bounds__(256) void bilinear_kernel(
    const float* __restrict__ x,     // [B][26][32]
    const float* __restrict__ W,     // [325][32][32]  W[p][e][d]
    const float* __restrict__ bias,  // [325][32]
    float* __restrict__ out)         // [B][325][32]
{
    const int p  = blockIdx.x;
    const int b0 = blockIdx.y * BT;

    // triu_indices(26, k=1) -> (fi, fj); wave-uniform scalar loop.
    int fi = 0, rem = p;
    #pragma unroll 1
    while (rem >= FIELD - 1 - fi) { rem -= FIELD - 1 - fi; ++fi; }
    const int fj = fi + 1 + rem;

    __shared__ float wT[EDIM][XPAD];   // wT[d][e] = W[p][e][d]
    __shared__ float xi[BT][XPAD];     // xi[br][d]

    const int tid = threadIdx.x;

    // ---- Stage W[p] (4 KB) transposed into LDS.
    // Global: thread t reads bytes [t*16, t*16+16) of W[p] -> perfectly linear.
    {
        const int e = tid >> 3;            // 0..31
        const int c = (tid & 7) << 2;      // 0..28 step 4 (d offset)
        const float4 w4 = *(const float4*)(W + ((size_t)p * EDIM + e) * EDIM + c);
        wT[c + 0][e] = w4.x;
        wT[c + 1][e] = w4.y;
        wT[c + 2][e] = w4.z;
        wT[c + 3][e] = w4.w;
    }
    // ---- Stage xi tile: 64 rows x 128 B, 2 coalesced float4 per thread.
    {
        const int s = tid >> 3;            // 0..31
        const int c = (tid & 7) << 2;
        #pragma unroll
        for (int h = 0; h < 2; ++h) {
            const int row = s + h * 32;
            const float4 v = *(const float4*)(x + (((size_t)(b0 + row)) * FIELD + fi) * EDIM + c);
            *(float4*)(&xi[row][c]) = v;
        }
    }
    __syncthreads();

    const int eg  = tid & 7;           // e-group
    const int e0  = eg << 2;           // 4 consecutive output e's
    const int br2 = tid >> 3;          // 0..31; thread handles rows br2, br2+32

    float acc[2][4] = {{0.f,0.f,0.f,0.f},{0.f,0.f,0.f,0.f}};

    #pragma unroll
    for (int d4 = 0; d4 < EDIM / 4; ++d4) {
        // broadcast, conflict-free (bank = 4*br + 4*d4 + j)
        const float4 xa = *(const float4*)(&xi[br2][d4 << 2]);
        const float4 xb = *(const float4*)(&xi[br2 + 32][d4 << 2]);
        const float xav[4] = {xa.x, xa.y, xa.z, xa.w};
        const float xbv[4] = {xb.x, xb.y, xb.z, xb.w};
        #pragma unroll
        for (int j = 0; j < 4; ++j) {
            const int d = (d4 << 2) + j;
            // broadcast, conflict-free (bank = 4*d + 4*eg + j, d uniform)
            const float4 w4 = *(const float4*)(&wT[d][e0]);
            acc[0][0] = fmaf(xav[j], w4.x, acc[0][0]);
            acc[0][1] = fmaf(xav[j], w4.y, acc[0][1]);
            acc[0][2] = fmaf(xav[j], w4.z, acc[0][2]);
            acc[0][3] = fmaf(xav[j], w4.w, acc[0][3]);
            acc[1][0] = fmaf(xbv[j], w4.x, acc[1][0]);
            acc[1][1] = fmaf(xbv[j], w4.y, acc[1][1]);
            acc[1][2] = fmaf(xbv[j], w4.z, acc[1][2]);
            acc[1][3] = fmaf(xbv[j], w4.w, acc[1][3]);
        }
    }

    // ---- Epilogue: bias + xj from cache, float4 stores.
    const float4 b4 = *(const float4*)(bias + (size_t)p * EDIM + e0);
    #pragma unroll
    for (int h = 0; h < 2; ++h) {
        const int b = b0 + br2 + h * 32;
        const float4 vj = *(const float4*)(x + ((size_t)b * FIELD + fj) * EDIM + e0);
        float4 r;
        r.x = (acc[h][0] + b4.x) * vj.x;
        r.y = (acc[h][1] + b4.y) * vj.y;
        r.z = (acc[h][2] + b4.z) * vj.z;
        r.w = (acc[h][3] + b4.w) * vj.w;
        *(float4*)(out + ((size_t)b * NPAIR + p) * EDIM + e0) = r;
    }
}

extern "C" void kernel_launch(void* const* d_in, const int* in_sizes, int n_in,
                              void* d_out, int out_size, void* d_ws, size_t ws_size,
                              hipStream_t stream) {
    const float* x    = (const float*)d_in[0];
    const float* W    = (const float*)d_in[1];
    const float* bias = (const float*)d_in[2];
    float* out        = (float*)d_out;

    const int B = in_sizes[0] / (FIELD * EDIM);   // 4096
    dim3 grid(NPAIR, B / BT);                      // p fastest -> batch tile stays L2-hot
    bilinear_kernel<<<grid, dim3(256), 0, stream>>>(x, W, bias, out);
}